// Round 1
// baseline (804.178 us; speedup 1.0000x reference)
//
#include <hip/hip_runtime.h>
#include <hip/hip_bf16.h>

// out[b,h,i,j] = scores[b,h,i,j] + slope(h) * (j - (S-1))
// shape (2, 16, 2048, 2048) fp32.  slope(h) = 2^(-8/16 * (h+1)) = 2^(-0.5*(h+1))
// Flat layout: idx = ((b*16 + h)*2048 + i)*2048 + j
//   j = idx & 2047            (2048 = 2^11)
//   h = (idx >> 22) & 15      (2048*2048 = 2^22)

__global__ __launch_bounds__(256)
void alibi_add_kernel(const float4* __restrict__ in, float4* __restrict__ out) {
    // one float4 (4 consecutive j) per thread; total/4 threads exactly
    const long long i4 = (long long)blockIdx.x * blockDim.x + threadIdx.x;
    const long long base = i4 * 4;                 // flat element index of .x

    const int j = (int)(base & 2047);              // column of first element
    const int h = (int)((base >> 22) & 15);        // head index

    const float slope = exp2f(-0.5f * (float)(h + 1));
    const float d0 = (float)(j - 2047);            // distance for .x

    float4 v = in[i4];
    v.x += slope * d0;
    v.y += slope * (d0 + 1.0f);
    v.z += slope * (d0 + 2.0f);
    v.w += slope * (d0 + 3.0f);
    out[i4] = v;
}

extern "C" void kernel_launch(void* const* d_in, const int* in_sizes, int n_in,
                              void* d_out, int out_size, void* d_ws, size_t ws_size,
                              hipStream_t stream) {
    const float4* in = (const float4*)d_in[0];
    float4* out = (float4*)d_out;

    const long long total = (long long)out_size;   // 2*16*2048*2048 = 134217728
    const long long n4 = total / 4;                // 33554432
    const int block = 256;
    const int grid = (int)(n4 / block);            // 131072, divides exactly

    alibi_add_kernel<<<grid, block, 0, stream>>>(in, out);
}